// Round 1
// baseline (3335.949 us; speedup 1.0000x reference)
//
#include <hip/hip_runtime.h>
#include <hip/hip_bf16.h>

#define EPS 1e-5f
#define MM 256     // MSA depth m
#define NN 384     // sequence length i/j
#define DM 256     // dim_msa
#define DH 32      // hidden dh
#define DP 128     // dim_pairwise
#define NIC (NN*DH)  // 12288

// ---------------------------------------------------------------------------
// K1: LayerNorm over DM + left/right projections (dm=256 -> dh=32 each),
// masked. One block (256 threads) per (m,i) row.
// Writes L[m][i*32+c], R[m][j*32+c] f32 (K-major layout for the big GEMM).
// ---------------------------------------------------------------------------
__global__ __launch_bounds__(256) void k1_ln_proj(
    const float* __restrict__ x, const int* __restrict__ mask,
    const float* __restrict__ ln_g, const float* __restrict__ ln_b,
    const float* __restrict__ wl, const float* __restrict__ bl,
    const float* __restrict__ wr, const float* __restrict__ br,
    float* __restrict__ L, float* __restrict__ R)
{
    const int row = blockIdx.x;          // row = m*NN + i
    const int t = threadIdx.x;
    __shared__ float xns[DM];
    __shared__ float red[8];
    __shared__ float part[4][64];

    float v = x[row*DM + t];
    float s = v, s2 = v*v;
    #pragma unroll
    for (int off = 32; off > 0; off >>= 1) {
        s  += __shfl_down(s, off, 64);
        s2 += __shfl_down(s2, off, 64);
    }
    if ((t & 63) == 0) { red[t>>6] = s; red[4 + (t>>6)] = s2; }
    __syncthreads();
    float mu   = (red[0]+red[1]+red[2]+red[3]) * (1.0f/DM);
    float var  = (red[4]+red[5]+red[6]+red[7]) * (1.0f/DM) - mu*mu;
    float rstd = rsqrtf(var + EPS);
    xns[t] = (v - mu) * rstd * ln_g[t] + ln_b[t];
    __syncthreads();

    // 64 outputs (32 left + 32 right), 4 k-slices of 64 each
    const int o  = t & 63;
    const int kw = t >> 6;
    const int oc = o & (DH-1);
    const float* __restrict__ w = (o < DH) ? wl : wr;
    float p = 0.f;
    #pragma unroll 8
    for (int kk = 0; kk < 64; kk++) {
        int k = kw*64 + kk;
        p += xns[k] * w[k*DH + oc];
    }
    part[kw][o] = p;
    __syncthreads();
    if (t < 64) {
        float sum4 = part[0][o] + part[1][o] + part[2][o] + part[3][o];
        float mf = (mask[row] != 0) ? 1.0f : 0.0f;
        if (o < DH) L[row*DH + o]  = (sum4 + bl[o])  * mf;
        else        R[row*DH + oc] = (sum4 + br[oc]) * mf;
    }
}

// ---------------------------------------------------------------------------
// K2: count[i,j] = sum_m mf[m,i]*mf[m,j]
// ---------------------------------------------------------------------------
__global__ __launch_bounds__(256) void k2_count(
    const int* __restrict__ mask, float* __restrict__ cnt)
{
    int id = blockIdx.x * 256 + threadIdx.x;   // 147456 = 384*384
    int i = id / NN, j = id % NN;
    float s = 0.f;
    for (int m = 0; m < MM; m++) {
        int a = (mask[m*NN + i] != 0);
        int b = (mask[m*NN + j] != 0);
        s += (float)(a & b);
    }
    cnt[id] = s;
}

// ---------------------------------------------------------------------------
// K3: big GEMM C[ic,jd] = sum_m L[m,ic] R[m,jd]  (M=N=12288, K=256)
// with fused projection:  out[i,j,p] = (C[i,:,j,:] . wo[:,p] + bo[p]) / (cnt+eps)
// 128x128 tile per block = 16 complete (i,j) pairs (4 i's x 4 j's).
// ---------------------------------------------------------------------------
#define BT 128
#define BK 16

__global__ __launch_bounds__(256) void k3_gemm_proj(
    const float* __restrict__ L, const float* __restrict__ R,
    const float* __restrict__ wo, const float* __restrict__ bo,
    const float* __restrict__ cnt, float* __restrict__ out)
{
    // smem: as[16][128] + bs[16][128] (16KB), reused as wos[32][132] (16.9KB)
    __shared__ float smem[4224];
    __shared__ __hip_bfloat16 gp[16][1032];   // padded stride: banks spread

    float* as = smem;
    float* bs = smem + BK*BT;

    const int t  = threadIdx.x;
    const int bx = blockIdx.x, by = blockIdx.y;
    const int tx = t & 15, ty = t >> 4;

    float acc[8][8];
    #pragma unroll
    for (int r = 0; r < 8; r++)
        #pragma unroll
        for (int c = 0; c < 8; c++) acc[r][c] = 0.f;

    for (int k0 = 0; k0 < MM; k0 += BK) {
        // stage A (L rows) and B (R rows): coalesced float4
        #pragma unroll
        for (int q = t; q < BK*BT/4; q += 256) {
            int kk = q >> 5, c4 = (q & 31) * 4;
            *(float4*)&as[kk*BT + c4] = *(const float4*)&L[(k0+kk)*NIC + bx*BT + c4];
            *(float4*)&bs[kk*BT + c4] = *(const float4*)&R[(k0+kk)*NIC + by*BT + c4];
        }
        __syncthreads();
        #pragma unroll
        for (int kk = 0; kk < BK; kk++) {
            float a[8], b[8];
            *(float4*)&a[0] = *(float4*)&as[kk*BT + ty*8];
            *(float4*)&a[4] = *(float4*)&as[kk*BT + ty*8 + 4];
            // b columns split {tx*4, 64+tx*4}: 2-way LDS aliasing only (free)
            *(float4*)&b[0] = *(float4*)&bs[kk*BT + tx*4];
            *(float4*)&b[4] = *(float4*)&bs[kk*BT + 64 + tx*4];
            #pragma unroll
            for (int r = 0; r < 8; r++)
                #pragma unroll
                for (int c = 0; c < 8; c++)
                    acc[r][c] += a[r] * b[c];
        }
        __syncthreads();
    }

    // scatter acc tile into per-pair layout gp[pair][c*32+d] (bf16)
    #pragma unroll
    for (int r = 0; r < 8; r++) {
        int rl = ty*8 + r;
        #pragma unroll
        for (int c = 0; c < 8; c++) {
            int cl = (c < 4) ? (tx*4 + c) : (64 + tx*4 + (c-4));
            int pair = ((rl >> 5) << 2) | (cl >> 5);
            int cd   = ((rl & 31) << 5) | (cl & 31);
            gp[pair][cd] = __float2bfloat16(acc[r][c]);
        }
    }

    // fused projection: each thread -> pair = t>>4, 8 outputs p in
    // {p0..p0+3, 64+p0..64+p0+3}, p0 = (t&15)*4  (2-way LDS aliasing)
    const int pair = t >> 4;
    const int p0 = (t & 15) * 4;
    float acc2[8];
    #pragma unroll
    for (int e = 0; e < 4; e++) { acc2[e] = bo[p0+e]; acc2[4+e] = bo[64+p0+e]; }

    float* wos = smem;   // [32][132]
    for (int kc = 0; kc < DH*DH; kc += 32) {
        __syncthreads();   // also orders gp writes before first reads
        #pragma unroll
        for (int q = t; q < 32*32; q += 256) {
            int kk = q >> 5, p4 = (q & 31) * 4;
            *(float4*)&wos[kk*132 + p4] = *(const float4*)&wo[(kc+kk)*DP + p4];
        }
        __syncthreads();
        #pragma unroll
        for (int kk = 0; kk < 32; kk++) {
            float g = __bfloat162float(gp[pair][kc+kk]);
            float4 w0 = *(float4*)&wos[kk*132 + p0];
            float4 w1 = *(float4*)&wos[kk*132 + 64 + p0];
            acc2[0] += g*w0.x; acc2[1] += g*w0.y; acc2[2] += g*w0.z; acc2[3] += g*w0.w;
            acc2[4] += g*w1.x; acc2[5] += g*w1.y; acc2[6] += g*w1.z; acc2[7] += g*w1.w;
        }
    }

    const int i = bx*4 + (pair >> 2), j = by*4 + (pair & 3);
    const float inv = 1.0f / (cnt[i*NN + j] + EPS);
    float4 o0 = make_float4(acc2[0]*inv, acc2[1]*inv, acc2[2]*inv, acc2[3]*inv);
    float4 o1 = make_float4(acc2[4]*inv, acc2[5]*inv, acc2[6]*inv, acc2[7]*inv);
    *(float4*)&out[(i*NN + j)*DP + p0]      = o0;
    *(float4*)&out[(i*NN + j)*DP + 64 + p0] = o1;
}

// ---------------------------------------------------------------------------
extern "C" void kernel_launch(void* const* d_in, const int* in_sizes, int n_in,
                              void* d_out, int out_size, void* d_ws, size_t ws_size,
                              hipStream_t stream)
{
    const float* x    = (const float*)d_in[0];
    const int*   mask = (const int*)d_in[1];
    const float* ln_g = (const float*)d_in[2];
    const float* ln_b = (const float*)d_in[3];
    const float* wl   = (const float*)d_in[4];
    const float* bl   = (const float*)d_in[5];
    const float* wr   = (const float*)d_in[6];
    const float* br   = (const float*)d_in[7];
    const float* wo   = (const float*)d_in[8];
    const float* bo   = (const float*)d_in[9];
    float* out = (float*)d_out;

    float* L   = (float*)d_ws;           // [MM][NIC] f32, 12.6 MB
    float* R   = L + (size_t)MM*NIC;     // [MM][NIC] f32, 12.6 MB
    float* cnt = R + (size_t)MM*NIC;     // [NN*NN]   f32, 0.6 MB

    k1_ln_proj<<<MM*NN, 256, 0, stream>>>(x, mask, ln_g, ln_b, wl, bl, wr, br, L, R);
    k2_count<<<(NN*NN)/256, 256, 0, stream>>>(mask, cnt);
    k3_gemm_proj<<<dim3(NIC/BT, NIC/BT), 256, 0, stream>>>(L, R, wo, bo, cnt, out);
}

// Round 3
// 671.878 us; speedup vs baseline: 4.9651x; 4.9651x over previous
//
#include <hip/hip_runtime.h>
#include <hip/hip_bf16.h>

#define EPS 1e-5f
#define MM 256     // MSA depth m
#define NN 384     // sequence length i/j
#define DM 256     // dim_msa
#define DH 32      // hidden dh
#define DP 128     // dim_pairwise
#define NIC (NN*DH)  // 12288

typedef __attribute__((ext_vector_type(8))) short short8;
typedef __attribute__((ext_vector_type(4))) float floatx4;

__device__ __forceinline__ void load16_to_lds(const void* gptr, void* lptr) {
    __builtin_amdgcn_global_load_lds(
        (const __attribute__((address_space(1))) void*)gptr,
        (__attribute__((address_space(3))) void*)lptr,
        16, 0, 0);
}

__device__ __forceinline__ unsigned short f2bf_bits(float f) {
    __hip_bfloat16 h = __float2bfloat16(f);
    union { __hip_bfloat16 h; unsigned short u; } cvt;
    cvt.h = h;
    return cvt.u;
}

// ---------------------------------------------------------------------------
// K1: LayerNorm + left/right projections, masked. Block per (m,i) row.
// Writes Lmb/Rmb bf16 in [m][ic] layout (transposed later by k1b).
// ---------------------------------------------------------------------------
__global__ __launch_bounds__(256) void k1_ln_proj(
    const float* __restrict__ x, const int* __restrict__ mask,
    const float* __restrict__ ln_g, const float* __restrict__ ln_b,
    const float* __restrict__ wl, const float* __restrict__ bl,
    const float* __restrict__ wr, const float* __restrict__ br,
    __hip_bfloat16* __restrict__ Lmb, __hip_bfloat16* __restrict__ Rmb)
{
    const int row = blockIdx.x;          // row = m*NN + i
    const int t = threadIdx.x;
    __shared__ float xns[DM];
    __shared__ float red[8];
    __shared__ float part[4][64];

    float v = x[(size_t)row*DM + t];
    float s = v, s2 = v*v;
    #pragma unroll
    for (int off = 32; off > 0; off >>= 1) {
        s  += __shfl_down(s, off, 64);
        s2 += __shfl_down(s2, off, 64);
    }
    if ((t & 63) == 0) { red[t>>6] = s; red[4 + (t>>6)] = s2; }
    __syncthreads();
    float mu   = (red[0]+red[1]+red[2]+red[3]) * (1.0f/DM);
    float var  = (red[4]+red[5]+red[6]+red[7]) * (1.0f/DM) - mu*mu;
    float rstd = rsqrtf(var + EPS);
    xns[t] = (v - mu) * rstd * ln_g[t] + ln_b[t];
    __syncthreads();

    const int o  = t & 63;
    const int kw = t >> 6;
    const int oc = o & (DH-1);
    const float* __restrict__ w = (o < DH) ? wl : wr;
    float p = 0.f;
    #pragma unroll 8
    for (int kk = 0; kk < 64; kk++) {
        int k = kw*64 + kk;
        p += xns[k] * w[k*DH + oc];
    }
    part[kw][o] = p;
    __syncthreads();
    if (t < 64) {
        float sum4 = part[0][o] + part[1][o] + part[2][o] + part[3][o];
        float mf = (mask[row] != 0) ? 1.0f : 0.0f;
        if (o < DH) Lmb[(size_t)row*DH + o]  = __float2bfloat16((sum4 + bl[o])  * mf);
        else        Rmb[(size_t)row*DH + oc] = __float2bfloat16((sum4 + br[oc]) * mf);
    }
}

// ---------------------------------------------------------------------------
// K1b: transpose [m][ic] bf16 -> [ic][m] bf16 for both L and R (z selects).
// ---------------------------------------------------------------------------
__global__ __launch_bounds__(256) void k1b_tr(
    const __hip_bfloat16* __restrict__ Lmb, const __hip_bfloat16* __restrict__ Rmb,
    __hip_bfloat16* __restrict__ Lb, __hip_bfloat16* __restrict__ Rb)
{
    __shared__ unsigned short ts[64*68];
    const unsigned short* src = (const unsigned short*)(blockIdx.z ? Rmb : Lmb);
    unsigned short* dst = (unsigned short*)(blockIdx.z ? Rb : Lb);
    const int ic0 = blockIdx.x*64, m0 = blockIdx.y*64;
    const int t = threadIdx.x;

    #pragma unroll
    for (int g = 0; g < 4; g++) {
        int s = g*256 + t;
        int row = s >> 4, c4 = (s & 15) * 4;
        *(ushort4*)&ts[row*68 + c4] =
            *(const ushort4*)&src[(size_t)(m0+row)*NIC + ic0 + c4];
    }
    __syncthreads();
    #pragma unroll
    for (int g = 0; g < 4; g++) {
        int s = g*256 + t;
        int icr = s >> 4, mq = (s & 15) * 4;
        ushort4 u;
        u.x = ts[(mq+0)*68 + icr];
        u.y = ts[(mq+1)*68 + icr];
        u.z = ts[(mq+2)*68 + icr];
        u.w = ts[(mq+3)*68 + icr];
        *(ushort4*)&dst[(size_t)(ic0+icr)*MM + m0 + mq] = u;
    }
}

// ---------------------------------------------------------------------------
// K0: transpose wo [1024 cd][128 p] f32 -> woT [128 p][1024 cd] bf16
// ---------------------------------------------------------------------------
__global__ __launch_bounds__(256) void k0_woT(
    const float* __restrict__ wo, __hip_bfloat16* __restrict__ woT)
{
    __shared__ float ts[64*129];
    const int cd0 = blockIdx.x * 64;
    const int t = threadIdx.x;
    #pragma unroll
    for (int g = 0; g < 8; g++) {
        int s = g*256 + t;
        int row = s >> 5, c4 = (s & 31) * 4;
        *(float4*)&ts[row*129 + c4] = *(const float4*)&wo[(size_t)(cd0+row)*DP + c4];
    }
    __syncthreads();
    unsigned short* dst = (unsigned short*)woT;
    #pragma unroll
    for (int g = 0; g < 8; g++) {
        int s = g*256 + t;
        int p = s >> 4, cq = (s & 15) * 4;
        ushort4 u;
        u.x = f2bf_bits(ts[(cq+0)*129 + p]);
        u.y = f2bf_bits(ts[(cq+1)*129 + p]);
        u.z = f2bf_bits(ts[(cq+2)*129 + p]);
        u.w = f2bf_bits(ts[(cq+3)*129 + p]);
        *(ushort4*)&dst[(size_t)p*1024 + cd0 + cq] = u;
    }
}

// ---------------------------------------------------------------------------
// K2: count[i,j] = sum_m mf[m,i]*mf[m,j]
// ---------------------------------------------------------------------------
__global__ __launch_bounds__(256) void k2_count(
    const int* __restrict__ mask, float* __restrict__ cnt)
{
    int id = blockIdx.x * 256 + threadIdx.x;
    int i = id / NN, j = id % NN;
    float s = 0.f;
    for (int m = 0; m < MM; m++) {
        int a = (mask[m*NN + i] != 0);
        int b = (mask[m*NN + j] != 0);
        s += (float)(a & b);
    }
    cnt[id] = s;
}

// ---------------------------------------------------------------------------
// K3: GEMM1 C[ic,jd] = sum_m Lb[ic,m] Rb[jd,m]   (bf16 MFMA 16x16x32)
// 128x128 tile, 4 waves 2x2, each wave 64x64 (4x4 MFMA tiles).
// Staging via global_load_lds w=16 with XOR swizzle on the GLOBAL side.
// Epilogue: gp[(iloc*384+j)*1024 + c*32+d] = bf16(C).
// ---------------------------------------------------------------------------
__global__ __launch_bounds__(256) void k3_gemm1(
    const __hip_bfloat16* __restrict__ Lb,   // [NIC][MM]
    const __hip_bfloat16* __restrict__ Rb,   // [NIC][MM]
    __hip_bfloat16* __restrict__ gp,         // [96*NN][1024] chunk-local
    int bx0)                                 // chunk offset in 128-row blocks
{
    __shared__ short Asm[128*64];
    __shared__ short Bsm[128*64];
    const int t = threadIdx.x;
    const int l = t & 63, w = t >> 6;
    const int wx = w & 1, wy = w >> 1;
    const int bx = blockIdx.x;               // 0..23 (chunk-local)
    const int by = blockIdx.y;               // 0..95

    const size_t arow0 = (size_t)(bx0 + bx) * 128;
    const size_t brow0 = (size_t)by * 128;

    floatx4 acc[4][4];
    #pragma unroll
    for (int a = 0; a < 4; a++)
        #pragma unroll
        for (int b = 0; b < 4; b++) acc[a][b] = (floatx4){0.f,0.f,0.f,0.f};

    for (int k0 = 0; k0 < MM; k0 += 64) {
        __syncthreads();
        #pragma unroll
        for (int g = 0; g < 4; g++) {
            int s = g*256 + t;
            int row = s >> 3;
            int ch = (s & 7) ^ (row & 7);
            load16_to_lds(Lb + (arow0 + row)*MM + k0 + ch*8, (char*)Asm + s*16);
            load16_to_lds(Rb + (brow0 + row)*MM + k0 + ch*8, (char*)Bsm + s*16);
        }
        __syncthreads();
        const int rlane = l & 15, kg = l >> 4;
        #pragma unroll
        for (int ks = 0; ks < 2; ks++) {
            short8 af[4], bf[4];
            #pragma unroll
            for (int tr = 0; tr < 4; tr++) {
                int r = wy*64 + tr*16 + rlane;
                int ch = (ks*4 + kg) ^ (r & 7);
                af[tr] = *(const short8*)((const char*)Asm + r*128 + ch*16);
            }
            #pragma unroll
            for (int tc = 0; tc < 4; tc++) {
                int r = wx*64 + tc*16 + rlane;
                int ch = (ks*4 + kg) ^ (r & 7);
                bf[tc] = *(const short8*)((const char*)Bsm + r*128 + ch*16);
            }
            #pragma unroll
            for (int tr = 0; tr < 4; tr++)
                #pragma unroll
                for (int tc = 0; tc < 4; tc++)
                    acc[tr][tc] = __builtin_amdgcn_mfma_f32_16x16x32_bf16(
                        af[tr], bf[tc], acc[tr][tc], 0, 0, 0);
        }
    }

    const int quad = l >> 4, lc = l & 15;
    #pragma unroll
    for (int tr = 0; tr < 4; tr++) {
        #pragma unroll
        for (int tc = 0; tc < 4; tc++) {
            int col = wx*64 + tc*16 + lc;            // 0..127
            int j = by*4 + (col >> 5);
            int d = col & 31;
            #pragma unroll
            for (int rg = 0; rg < 4; rg++) {
                int row = wy*64 + tr*16 + quad*4 + rg;   // 0..127
                int iloc = bx*4 + (row >> 5);            // chunk-local i
                int c = row & 31;
                gp[((size_t)(iloc*NN + j))*1024 + c*32 + d] =
                    __float2bfloat16(acc[tr][tc][rg]);
            }
        }
    }
}

// ---------------------------------------------------------------------------
// K4: GEMM2 out[ij,p] = (gp[ij,:] . woT[p,:] + bo[p]) / (cnt[ij]+eps)
// M=36864 per chunk, K=1024, N=128. Same MFMA structure as K3.
// ---------------------------------------------------------------------------
__global__ __launch_bounds__(256) void k4_gemm2(
    const __hip_bfloat16* __restrict__ gp,    // [36864][1024] chunk-local
    const __hip_bfloat16* __restrict__ woT,   // [128][1024]
    const float* __restrict__ bo, const float* __restrict__ cnt,
    float* __restrict__ out, int ij0)
{
    __shared__ short Asm[128*64];
    __shared__ short Bsm[128*64];
    const int t = threadIdx.x;
    const int l = t & 63, w = t >> 6;
    const int wx = w & 1, wy = w >> 1;
    const int bm = blockIdx.x;               // 0..287

    floatx4 acc[4][4];
    #pragma unroll
    for (int a = 0; a < 4; a++)
        #pragma unroll
        for (int b = 0; b < 4; b++) acc[a][b] = (floatx4){0.f,0.f,0.f,0.f};

    for (int k0 = 0; k0 < DH*DH; k0 += 64) {
        __syncthreads();
        #pragma unroll
        for (int g = 0; g < 4; g++) {
            int s = g*256 + t;
            int row = s >> 3;
            int ch = (s & 7) ^ (row & 7);
            load16_to_lds(gp + ((size_t)(bm*128 + row))*1024 + k0 + ch*8,
                          (char*)Asm + s*16);
            load16_to_lds(woT + (size_t)row*1024 + k0 + ch*8,
                          (char*)Bsm + s*16);
        }
        __syncthreads();
        const int rlane = l & 15, kg = l >> 4;
        #pragma unroll
        for (int ks = 0; ks < 2; ks++) {
            short8 af[4], bf[4];
            #pragma unroll
            for (int tr = 0; tr < 4; tr++) {
                int r = wy*64 + tr*16 + rlane;
                int ch = (ks*4 + kg) ^ (r & 7);
                af[tr] = *(const short8*)((const char*)Asm + r*128 + ch*16);
            }
            #pragma unroll
            for (int tc = 0; tc < 4; tc++) {
                int r = wx*64 + tc*16 + rlane;
                int ch = (ks*4 + kg) ^ (r & 7);
                bf[tc] = *(const short8*)((const char*)Bsm + r*128 + ch*16);
            }
            #pragma unroll
            for (int tr = 0; tr < 4; tr++)
                #pragma unroll
                for (int tc = 0; tc < 4; tc++)
                    acc[tr][tc] = __builtin_amdgcn_mfma_f32_16x16x32_bf16(
                        af[tr], bf[tc], acc[tr][tc], 0, 0, 0);
        }
    }

    const int quad = l >> 4, lc = l & 15;
    #pragma unroll
    for (int tr = 0; tr < 4; tr++) {
        #pragma unroll
        for (int rg = 0; rg < 4; rg++) {
            int ijl = bm*128 + wy*64 + tr*16 + quad*4 + rg;
            int ij = ij0 + ijl;
            float inv = 1.0f / (cnt[ij] + EPS);
            #pragma unroll
            for (int tc = 0; tc < 4; tc++) {
                int p = wx*64 + tc*16 + lc;
                out[(size_t)ij*DP + p] = (acc[tr][tc][rg] + bo[p]) * inv;
            }
        }
    }
}

// ---------------------------------------------------------------------------
extern "C" void kernel_launch(void* const* d_in, const int* in_sizes, int n_in,
                              void* d_out, int out_size, void* d_ws, size_t ws_size,
                              hipStream_t stream)
{
    const float* x    = (const float*)d_in[0];
    const int*   mask = (const int*)d_in[1];
    const float* ln_g = (const float*)d_in[2];
    const float* ln_b = (const float*)d_in[3];
    const float* wl   = (const float*)d_in[4];
    const float* bl   = (const float*)d_in[5];
    const float* wr   = (const float*)d_in[6];
    const float* br   = (const float*)d_in[7];
    const float* wo   = (const float*)d_in[8];
    const float* bo   = (const float*)d_in[9];
    float* out = (float*)d_out;

    char* ws = (char*)d_ws;
    size_t off = 0;
    __hip_bfloat16* Lmb = (__hip_bfloat16*)(ws + off); off += (size_t)MM*NIC*2;   // 6.29 MB
    __hip_bfloat16* Rmb = (__hip_bfloat16*)(ws + off); off += (size_t)MM*NIC*2;
    __hip_bfloat16* Lb  = (__hip_bfloat16*)(ws + off); off += (size_t)NIC*MM*2;
    __hip_bfloat16* Rb  = (__hip_bfloat16*)(ws + off); off += (size_t)NIC*MM*2;
    __hip_bfloat16* woT = (__hip_bfloat16*)(ws + off); off += (size_t)DP*1024*2;  // 0.26 MB
    float*          cnt = (float*)(ws + off);          off += (size_t)NN*NN*4;    // 0.59 MB
    __hip_bfloat16* gpb = (__hip_bfloat16*)(ws + off); // 96*NN*1024*2 = 75.5 MB per chunk

    k1_ln_proj<<<MM*NN, 256, 0, stream>>>(x, mask, ln_g, ln_b, wl, bl, wr, br, Lmb, Rmb);
    k2_count<<<(NN*NN)/256, 256, 0, stream>>>(mask, cnt);
    k0_woT<<<16, 256, 0, stream>>>(wo, woT);
    k1b_tr<<<dim3(NIC/64, MM/64, 2), 256, 0, stream>>>(Lmb, Rmb, Lb, Rb);

    // 4 chunks of 96 i-values each: gp buffer reused; stream order serializes.
    for (int c = 0; c < 4; c++) {
        k3_gemm1<<<dim3(24, 96), 256, 0, stream>>>(Lb, Rb, gpb, c*24);
        k4_gemm2<<<288, 256, 0, stream>>>(gpb, woT, bo, cnt, out, c*96*NN);
    }
}

// Round 4
// 554.806 us; speedup vs baseline: 6.0128x; 1.2110x over previous
//
#include <hip/hip_runtime.h>
#include <hip/hip_bf16.h>

#define EPS 1e-5f
#define MM 256     // MSA depth m
#define NN 384     // sequence length i/j
#define DM 256     // dim_msa
#define DH 32      // hidden dh
#define DP 128     // dim_pairwise
#define NIC (NN*DH)  // 12288

typedef __attribute__((ext_vector_type(8))) short short8;
typedef __attribute__((ext_vector_type(4))) float floatx4;

__device__ __forceinline__ void load16_to_lds(const void* gptr, void* lptr) {
    __builtin_amdgcn_global_load_lds(
        (const __attribute__((address_space(1))) void*)gptr,
        (__attribute__((address_space(3))) void*)lptr,
        16, 0, 0);
}

__device__ __forceinline__ unsigned short f2bf_bits(float f) {
    __hip_bfloat16 h = __float2bfloat16(f);
    union { __hip_bfloat16 h; unsigned short u; } cvt;
    cvt.h = h;
    return cvt.u;
}

// ---------------------------------------------------------------------------
// K0a: transpose wo [1024 cd][128 p] f32 -> woT [128 p][1024 cd] bf16
// ---------------------------------------------------------------------------
__global__ __launch_bounds__(256) void k0a_woT(
    const float* __restrict__ wo, unsigned short* __restrict__ woT)
{
    __shared__ float ts[64*129];
    const int cd0 = blockIdx.x * 64;
    const int t = threadIdx.x;
    #pragma unroll
    for (int g = 0; g < 8; g++) {
        int s = g*256 + t;
        int row = s >> 5, c4 = (s & 31) * 4;
        *(float4*)&ts[row*129 + c4] = *(const float4*)&wo[(size_t)(cd0+row)*DP + c4];
    }
    __syncthreads();
    #pragma unroll
    for (int g = 0; g < 8; g++) {
        int s = g*256 + t;
        int p = s >> 4, cq = (s & 15) * 4;
        ushort4 u;
        u.x = f2bf_bits(ts[(cq+0)*129 + p]);
        u.y = f2bf_bits(ts[(cq+1)*129 + p]);
        u.z = f2bf_bits(ts[(cq+2)*129 + p]);
        u.w = f2bf_bits(ts[(cq+3)*129 + p]);
        *(ushort4*)&woT[(size_t)p*1024 + cd0 + cq] = u;
    }
}

// ---------------------------------------------------------------------------
// K0b: build WbT[64 c][256 k] bf16 (c<32: wl col, else wr col) + bias[64] f32
// ---------------------------------------------------------------------------
__global__ __launch_bounds__(256) void k0b_w(
    const float* __restrict__ wl, const float* __restrict__ bl,
    const float* __restrict__ wr, const float* __restrict__ br,
    unsigned short* __restrict__ WbT, float* __restrict__ bias)
{
    const int t = threadIdx.x;
    for (int g = 0; g < 64; g++) {
        int idx = g*256 + t;
        int c = idx >> 8, k = idx & 255;
        float v = (c < DH) ? wl[k*DH + c] : wr[k*DH + (c - DH)];
        WbT[c*256 + k] = f2bf_bits(v);
    }
    if (t < 64) bias[t] = (t < DH) ? bl[t] : br[t - DH];
}

// ---------------------------------------------------------------------------
// K2: count[i,j] = sum_m mf[m,i]*mf[m,j]
// ---------------------------------------------------------------------------
__global__ __launch_bounds__(256) void k2_count(
    const int* __restrict__ mask, float* __restrict__ cnt)
{
    int id = blockIdx.x * 256 + threadIdx.x;
    int i = id / NN, j = id % NN;
    float s = 0.f;
    for (int m = 0; m < MM; m++) {
        int a = (mask[m*NN + i] != 0);
        int b = (mask[m*NN + j] != 0);
        s += (float)(a & b);
    }
    cnt[id] = s;
}

// ---------------------------------------------------------------------------
// K1: LN (f32, wave-reduce) + MFMA projection, writing Lb/Rb directly in
// [ic][m] (K-major) layout. Block = (i = blockIdx.x, m-chunk of 64 rows).
// ---------------------------------------------------------------------------
__global__ __launch_bounds__(256) void k1_lnproj(
    const float* __restrict__ x, const int* __restrict__ mask,
    const float* __restrict__ ln_g, const float* __restrict__ ln_b,
    const unsigned short* __restrict__ WbTg, const float* __restrict__ bias,
    unsigned short* __restrict__ Lb, unsigned short* __restrict__ Rb)
{
    __shared__ unsigned short xns[64*264];   // [mlocal][k] padded (+8)
    __shared__ unsigned short wbt[64*264];   // [c][k] padded
    __shared__ float mfs[64];

    const int i  = blockIdx.x;
    const int mc = blockIdx.y;               // m-chunk (64 rows)
    const int t = threadIdx.x;
    const int l = t & 63, w = t >> 6;
    const int lc = l & 15, quad = l >> 4;

    // stage WbT into LDS (padded rows)
    #pragma unroll
    for (int g = 0; g < 16; g++) {
        int q = g*256 + t;                    // 4096 ushort4 chunks
        int row = q >> 6, off = (q & 63) * 4;
        *(ushort4*)&wbt[row*264 + off] = *(const ushort4*)&WbTg[row*256 + off];
    }

    // per-lane gamma/beta (k = l*4..l*4+3)
    float4 g4 = *(const float4*)&ln_g[l*4];
    float4 b4 = *(const float4*)&ln_b[l*4];

    // LN: wave w handles rows w*16 .. w*16+15
    for (int rr = 0; rr < 16; rr++) {
        int mlocal = w*16 + rr;
        int m = mc*64 + mlocal;
        size_t grow = (size_t)m*NN + i;
        float4 v = *(const float4*)&x[grow*DM + l*4];
        float s  = v.x + v.y + v.z + v.w;
        float s2 = v.x*v.x + v.y*v.y + v.z*v.z + v.w*v.w;
        #pragma unroll
        for (int off = 1; off < 64; off <<= 1) {
            s  += __shfl_xor(s,  off, 64);
            s2 += __shfl_xor(s2, off, 64);
        }
        float mu   = s * (1.0f/DM);
        float var  = s2 * (1.0f/DM) - mu*mu;
        float rstd = rsqrtf(var + EPS);
        ushort4 u;
        u.x = f2bf_bits((v.x - mu)*rstd*g4.x + b4.x);
        u.y = f2bf_bits((v.y - mu)*rstd*g4.y + b4.y);
        u.z = f2bf_bits((v.z - mu)*rstd*g4.z + b4.z);
        u.w = f2bf_bits((v.w - mu)*rstd*g4.w + b4.w);
        *(ushort4*)&xns[mlocal*264 + l*4] = u;
        if (l == 0) mfs[mlocal] = (mask[grow] != 0) ? 1.0f : 0.0f;
    }
    __syncthreads();

    // MFMA: D[m][c] = sum_k xn[m][k] * WbT[c][k]; wave = M-tile w, 4 N-tiles
    floatx4 acc[4];
    #pragma unroll
    for (int nt = 0; nt < 4; nt++) acc[nt] = (floatx4){0.f,0.f,0.f,0.f};
    #pragma unroll
    for (int ks = 0; ks < 8; ks++) {
        short8 af = *(const short8*)&xns[(w*16 + lc)*264 + ks*32 + quad*8];
        #pragma unroll
        for (int nt = 0; nt < 4; nt++) {
            short8 bf = *(const short8*)&wbt[(nt*16 + lc)*264 + ks*32 + quad*8];
            acc[nt] = __builtin_amdgcn_mfma_f32_16x16x32_bf16(af, bf, acc[nt], 0, 0, 0);
        }
    }
    __syncthreads();   // done reading xns; reuse as transpose buffer

    // bias + mask, write transposed tile tr[c][mlocal]
    unsigned short* tr = xns;   // [64][72]
    #pragma unroll
    for (int nt = 0; nt < 4; nt++) {
        int c = nt*16 + lc;
        float bv = bias[c];
        #pragma unroll
        for (int rg = 0; rg < 4; rg++) {
            int mlocal = w*16 + quad*4 + rg;
            tr[c*72 + mlocal] = f2bf_bits((acc[nt][rg] + bv) * mfs[mlocal]);
        }
    }
    __syncthreads();

    // write out: thread t -> c = t>>2, m-segment (t&3)*16 (contig in m)
    {
        int c = t >> 2, seg = t & 3;
        unsigned short* dst = (c < DH)
            ? &Lb[((size_t)(i*DH + c))*MM + mc*64 + seg*16]
            : &Rb[((size_t)(i*DH + (c - DH)))*MM + mc*64 + seg*16];
        #pragma unroll
        for (int q = 0; q < 4; q++)
            *(ushort4*)&dst[q*4] = *(ushort4*)&tr[c*72 + seg*16 + q*4];
    }
}

// ---------------------------------------------------------------------------
// K3f: fused GEMM1 + projection.
// GEMM1: C[ic,jd] = sum_m Lb[ic,m] Rb[jd,m] (128x128 tile, bf16 MFMA).
// Epilogue: acc -> LDS gp[16 pairs][1024 cd] bf16, then
// GEMM2: out[pair,p] = (gp[pair,:].woT[p,:] + bo[p]) / (cnt+eps).
// ---------------------------------------------------------------------------
__global__ __launch_bounds__(256) void k3f_gemm(
    const unsigned short* __restrict__ Lb,   // [NIC][MM]
    const unsigned short* __restrict__ Rb,   // [NIC][MM]
    const unsigned short* __restrict__ woT,  // [128 p][1024 cd]
    const float* __restrict__ bo, const float* __restrict__ cnt,
    float* __restrict__ out)
{
    __shared__ short smem_u[16520];          // union: Asm/Bsm | gp[16][1032]
    short* Asm = smem_u;                     // [128][64]
    short* Bsm = smem_u + 128*64;
    const int t = threadIdx.x;
    const int l = t & 63, w = t >> 6;
    const int wx = w & 1, wy = w >> 1;
    const int lc = l & 15, quad = l >> 4;
    const int bx = blockIdx.x, by = blockIdx.y;

    const size_t arow0 = (size_t)bx * 128;
    const size_t brow0 = (size_t)by * 128;

    floatx4 acc[4][4];
    #pragma unroll
    for (int a = 0; a < 4; a++)
        #pragma unroll
        for (int b = 0; b < 4; b++) acc[a][b] = (floatx4){0.f,0.f,0.f,0.f};

    for (int k0 = 0; k0 < MM; k0 += 64) {
        __syncthreads();
        #pragma unroll
        for (int g = 0; g < 4; g++) {
            int s = g*256 + t;
            int row = s >> 3;
            int ch = (s & 7) ^ (row & 7);
            load16_to_lds(Lb + (arow0 + row)*MM + k0 + ch*8, (char*)Asm + s*16);
            load16_to_lds(Rb + (brow0 + row)*MM + k0 + ch*8, (char*)Bsm + s*16);
        }
        __syncthreads();
        #pragma unroll
        for (int ks = 0; ks < 2; ks++) {
            short8 af[4], bf[4];
            #pragma unroll
            for (int tr = 0; tr < 4; tr++) {
                int r = wy*64 + tr*16 + lc;
                int ch = (ks*4 + quad) ^ (r & 7);
                af[tr] = *(const short8*)((const char*)Asm + r*128 + ch*16);
            }
            #pragma unroll
            for (int tc = 0; tc < 4; tc++) {
                int r = wx*64 + tc*16 + lc;
                int ch = (ks*4 + quad) ^ (r & 7);
                bf[tc] = *(const short8*)((const char*)Bsm + r*128 + ch*16);
            }
            #pragma unroll
            for (int tr = 0; tr < 4; tr++)
                #pragma unroll
                for (int tc = 0; tc < 4; tc++)
                    acc[tr][tc] = __builtin_amdgcn_mfma_f32_16x16x32_bf16(
                        af[tr], bf[tc], acc[tr][tc], 0, 0, 0);
        }
    }

    __syncthreads();   // all waves done with Asm/Bsm frag reads
    // scatter acc -> gp[pair][cd], pair = (row>>5)*4 + (col>>5), cd = c*32+d
    short* gpL = smem_u;   // [16][1032] (pad +8 shorts per row)
    #pragma unroll
    for (int tr = 0; tr < 4; tr++) {
        #pragma unroll
        for (int tc = 0; tc < 4; tc++) {
            int col = wx*64 + tc*16 + lc;
            int jl = col >> 5, d = col & 31;
            #pragma unroll
            for (int rg = 0; rg < 4; rg++) {
                int row = wy*64 + tr*16 + quad*4 + rg;
                int il = row >> 5, c = row & 31;
                gpL[(il*4 + jl)*1032 + c*32 + d] =
                    (short)f2bf_bits(acc[tr][tc][rg]);
            }
        }
    }
    __syncthreads();

    // GEMM2: M=16 pairs, K=1024, N=128; wave w -> p-tiles {2w, 2w+1}
    floatx4 acc2[2];
    acc2[0] = (floatx4){0.f,0.f,0.f,0.f};
    acc2[1] = (floatx4){0.f,0.f,0.f,0.f};
    #pragma unroll 4
    for (int ks = 0; ks < 32; ks++) {
        short8 a2 = *(const short8*)&gpL[lc*1032 + ks*32 + quad*8];
        #pragma unroll
        for (int nt = 0; nt < 2; nt++) {
            int pcol = (w*2 + nt)*16 + lc;
            short8 b2 = *(const short8*)&woT[(size_t)pcol*1024 + ks*32 + quad*8];
            acc2[nt] = __builtin_amdgcn_mfma_f32_16x16x32_bf16(a2, b2, acc2[nt], 0, 0, 0);
        }
    }

    #pragma unroll
    for (int nt = 0; nt < 2; nt++) {
        int pcol = (w*2 + nt)*16 + lc;
        float bv = bo[pcol];
        #pragma unroll
        for (int rg = 0; rg < 4; rg++) {
            int pair = quad*4 + rg;
            int i = bx*4 + (pair >> 2), j = by*4 + (pair & 3);
            float inv = 1.0f / (cnt[i*NN + j] + EPS);
            out[((size_t)(i*NN + j))*DP + pcol] = (acc2[nt][rg] + bv) * inv;
        }
    }
}

// ---------------------------------------------------------------------------
extern "C" void kernel_launch(void* const* d_in, const int* in_sizes, int n_in,
                              void* d_out, int out_size, void* d_ws, size_t ws_size,
                              hipStream_t stream)
{
    const float* x    = (const float*)d_in[0];
    const int*   mask = (const int*)d_in[1];
    const float* ln_g = (const float*)d_in[2];
    const float* ln_b = (const float*)d_in[3];
    const float* wl   = (const float*)d_in[4];
    const float* bl   = (const float*)d_in[5];
    const float* wr   = (const float*)d_in[6];
    const float* br   = (const float*)d_in[7];
    const float* wo   = (const float*)d_in[8];
    const float* bo   = (const float*)d_in[9];
    float* out = (float*)d_out;

    char* ws = (char*)d_ws;
    size_t off = 0;
    unsigned short* Lb   = (unsigned short*)(ws + off); off += (size_t)NIC*MM*2;  // 6.29 MB
    unsigned short* Rb   = (unsigned short*)(ws + off); off += (size_t)NIC*MM*2;  // 6.29 MB
    unsigned short* woT  = (unsigned short*)(ws + off); off += (size_t)DP*1024*2; // 0.26 MB
    unsigned short* WbTg = (unsigned short*)(ws + off); off += (size_t)64*256*2;  // 32 KB
    float*          bias = (float*)(ws + off);          off += 64*4;
    float*          cnt  = (float*)(ws + off);          off += (size_t)NN*NN*4;   // 0.59 MB

    k0a_woT<<<16, 256, 0, stream>>>(wo, woT);
    k0b_w<<<1, 256, 0, stream>>>(wl, bl, wr, br, WbTg, bias);
    k2_count<<<(NN*NN)/256, 256, 0, stream>>>(mask, cnt);
    k1_lnproj<<<dim3(NN, MM/64), 256, 0, stream>>>(x, mask, ln_g, ln_b, WbTg, bias, Lb, Rb);
    k3f_gemm<<<dim3(NIC/128, NIC/128), 256, 0, stream>>>(Lb, Rb, woT, bo, cnt, out);
}